// Round 5
// baseline (201.879 us; speedup 1.0000x reference)
//
#include <hip/hip_runtime.h>
#include <cmath>

namespace {
constexpr int T = 1024, BATCH = 128, U = 100, E = 100, P = 20, C = 2;
constexpr int TC = 64, NC = 16;          // chunk size, number of chunks
constexpr float DT = 0.001f, SCALE = 0.2f, MU = 1.0f;
constexpr float DTS = DT * SCALE;

// ---- LDS arena ----
// region0 [0,51200): prologue = WL (100 j x 464B, f16 w1 k'-interleaved, pads 0)
//                    main loop = EB f32 [2 parity][64 t][400 B]
// ZB [51200,110592): [2][64 t][464 B] f16 z, (x_j,y_j) at byte 4j, pads [400,464)=0
// HB [110592,136192): [2][64 t][200 B] f16 h1
constexpr uint32_t WROW = 464u, ZROW = 464u, HROW = 200u;
constexpr uint32_t EBUF = 25600u;
constexpr uint32_t ZBB = 51200u, ZBUF = 29696u;
constexpr uint32_t HBB = 110592u, HBUF = 12800u;
constexpr uint32_t ARENA = 136192u;

typedef _Float16 f16x8 __attribute__((ext_vector_type(8)));
typedef float f32x4 __attribute__((ext_vector_type(4)));
typedef _Float16 h2_t __attribute__((ext_vector_type(2)));

#define AS1 __attribute__((address_space(1)))
#define AS3 __attribute__((address_space(3)))

__device__ __forceinline__ void eul5(float& xx, float& yy, float dom, float ax) {
    constexpr float c0 = 1.0f + DT * MU;   // dom = DT*omega, ax = DT*SCALE*drive
#pragma unroll
    for (int s = 0; s < 5; ++s) {
        float r2 = fmaf(yy, yy, xx * xx);
        float sc = fmaf(-DT, r2, c0);
        float nx = fmaf(xx, sc, fmaf(-dom, yy, ax));
        float ny = fmaf(yy, sc, dom * xx);
        xx = nx; yy = ny;
    }
}

__launch_bounds__(384, 2)
__global__ void donn_kernel(const int* __restrict__ xg,
                            const float* __restrict__ emb,
                            const float* __restrict__ omega1,
                            const float* __restrict__ omega2,
                            const float* __restrict__ w1,
                            const float* __restrict__ b1,
                            const float* __restrict__ w2,
                            const float* __restrict__ b2,
                            const float* __restrict__ wp,
                            const float* __restrict__ bp,
                            const float* __restrict__ wh,
                            const float* __restrict__ bh,
                            float* __restrict__ out)
{
    const int b = blockIdx.x;
    const int tid = threadIdx.x;

    __shared__ __align__(16) char smem[ARENA];
    __shared__ int xs[2][TC];
    __shared__ float zf2[2][104];
    __shared__ float pb[2][104];
    __shared__ float h2s[104];
    __shared__ float h3s[32];

    // ---- per-role persistent state ----
    float x1 = 0.f, y1 = 0.f, x2 = 0.f, y2 = 0.f;   // osc (tid<128, j=tid<100)
    float dom1 = 0.f, dom2 = 0.f;
    int mh = 0, n0 = 0, lane = 0;                    // mm (tid>=128)
    float b1r[4] = {0.f, 0.f, 0.f, 0.f};
    f16x8 Bf[4][7];                                  // hoisted w1 fragments

    const bool is_osc = (tid < 128);
    if (is_osc) {
        const int j = (tid < U) ? tid : (U - 1);
        dom1 = DT * omega1[j];
        dom2 = DT * omega2[j];
    } else {
        const int mw = (tid >> 6) - 2;               // 0..3
        lane = tid & 63;
        mh = mw >> 1;                                // m-half: rows [mh*32, mh*32+32)
        n0 = (mw & 1) * 4;                           // n-tiles n0..n0+3 (tile 7 dummy)
    }

    // ---- prologue step 1: xs, WL stage + pads, ZB pads ----
    if (tid < TC) xs[0][tid] = xg[b * T + tid];
    else if (tid < 2 * TC) xs[1][tid - TC] = xg[b * T + TC + (tid - TC)];
    for (int idx = tid; idx < 200 * 100; idx += 384) {
        int k = idx / 100, j = idx - 100 * k;
        int kp = (k < U) ? (2 * k) : (2 * (k - U) + 1);
        *(_Float16*)(smem + (uint32_t)j * WROW + 2 * kp) = (_Float16)w1[k * U + j];
    }
    for (int idx = tid; idx < 100 * 16; idx += 384) {          // WL pads [400,464)
        int row = idx >> 4, wd = idx & 15;
        *(float*)(smem + (uint32_t)row * WROW + 400u + 4u * (uint32_t)wd) = 0.f;
    }
    for (int idx = tid; idx < 128 * 16; idx += 384) {          // ZB pads [400,464)
        int zr = idx >> 4, wd = idx & 15;
        uint32_t base = ZBB + (uint32_t)(zr >> 6) * ZBUF + (uint32_t)(zr & 63) * ZROW;
        *(float*)(smem + base + 400u + 4u * (uint32_t)wd) = 0.f;
    }
    __syncthreads();

    // ---- prologue step 2: mm waves hoist B-frags ----
    if (!is_osc) {
#pragma unroll
        for (int n = 0; n < 4; ++n) {
            int j = (n0 + n) * 16 + (lane & 15);
            int jj = (j < U) ? j : (U - 1);
            b1r[n] = b1[jj];
            uint32_t br = (uint32_t)jj * WROW + 16u * (uint32_t)(lane >> 4);
#pragma unroll
            for (int ks = 0; ks < 7; ++ks)
                Bf[n][ks] = *(const f16x8*)(smem + br + 64u * ks);
        }
    }
    __syncthreads();

    // ---- prologue step 3: EB chunk 0 (f32, overlays WL) ----
    for (int idx = tid; idx < TC * E; idx += 384) {
        int t = idx / 100, c = idx - 100 * t;
        int tok = xs[0][t];
        *(float*)(smem + (uint32_t)t * 400u + 4u * (uint32_t)c) = emb[tok * E + c];
    }
    __syncthreads();

    // ---- 3-stage chunked pipeline, one barrier per phase ----
    // phase p: osc waves do L1 chunk p (EB[p&1] -> ZB[p&1]) and L2 chunk p-2
    // (HB[p&1]); mm waves DMA EB chunk p+1 -> EB[(p+1)&1] then MFMA chunk p-1
    // (ZB[(p-1)&1] -> HB[(p-1)&1]).
    for (int p = 0; p <= NC + 1; ++p) {
        if (is_osc) {
            if (tid < TC && p + 2 < NC)
                xs[p & 1][tid] = xg[b * T + (p + 2) * TC + tid];
            if (tid < U) {
                const bool do1 = p < NC, do2 = p >= 2;
                const float* eb = (const float*)(smem + (uint32_t)(p & 1) * EBUF);
                const char* hb = smem + HBB + (uint32_t)(p & 1) * HBUF;
                char* zb = smem + ZBB + (uint32_t)(p & 1) * ZBUF;
                if (do1 && do2) {
#pragma unroll 4
                    for (int tl = 0; tl < TC; ++tl) {
                        float u = eb[tl * 100 + tid];
                        eul5(x1, y1, dom1, DTS * u);
                        h2_t zz; zz[0] = (_Float16)x1; zz[1] = (_Float16)y1;
                        *(h2_t*)(zb + (uint32_t)tl * ZROW + 4u * (uint32_t)tid) = zz;
                        float hv = (float)(*(const _Float16*)(hb + (uint32_t)tl * HROW + 2u * (uint32_t)tid));
                        eul5(x2, y2, dom2, DTS * hv);
                    }
                } else if (do1) {
#pragma unroll 4
                    for (int tl = 0; tl < TC; ++tl) {
                        float u = eb[tl * 100 + tid];
                        eul5(x1, y1, dom1, DTS * u);
                        h2_t zz; zz[0] = (_Float16)x1; zz[1] = (_Float16)y1;
                        *(h2_t*)(zb + (uint32_t)tl * ZROW + 4u * (uint32_t)tid) = zz;
                    }
                } else if (do2) {
#pragma unroll 4
                    for (int tl = 0; tl < TC; ++tl) {
                        float hv = (float)(*(const _Float16*)(hb + (uint32_t)tl * HROW + 2u * (uint32_t)tid));
                        eul5(x2, y2, dom2, DTS * hv);
                    }
                }
            }
        } else {
            const int mw = mh * 2 + (n0 >> 2);       // reconstruct 0..3
            // A) DMA emb gather for chunk p+1 into EB[(p+1)&1] (fire-and-forget)
            if (p + 1 < NC) {
                const uint32_t qe = (uint32_t)((p + 1) & 1);
#pragma unroll
                for (int i = 0; i < 25; ++i) {
                    int f = (mw * 25 + i) * 64 + lane;
                    int t = f / 100;
                    int c = f - 100 * t;
                    int tok = xs[qe][t];
                    const float* g = emb + tok * E + c;
                    char* l = smem + qe * EBUF + (uint32_t)(mw * 25 + i) * 256u;
                    __builtin_amdgcn_global_load_lds((const AS1 void*)(const void*)g,
                                                     (AS3 void*)(void*)l, 4, 0, 0);
                }
            }
            // B) MFMA GEMM chunk p-1: C[64t x 100j] = z[64x224] * w1'[224x100]
            if (p >= 1 && p <= NC) {
                const uint32_t qm = (uint32_t)((p - 1) & 1);
                const char* zb = smem + ZBB + qm * ZBUF;
                char* hb = smem + HBB + qm * HBUF;
                f32x4 acc[2][4];
#pragma unroll
                for (int mt = 0; mt < 2; ++mt)
#pragma unroll
                    for (int n = 0; n < 4; ++n) acc[mt][n] = (f32x4)0.f;
#pragma unroll
                for (int mt = 0; mt < 2; ++mt) {
                    const uint32_t ar = (uint32_t)(mh * 32 + mt * 16 + (lane & 15)) * ZROW
                                        + 16u * (uint32_t)(lane >> 4);
                    f16x8 af[7];
#pragma unroll
                    for (int ks = 0; ks < 7; ++ks)
                        af[ks] = *(const f16x8*)(zb + ar + 64u * ks);
#pragma unroll
                    for (int n = 0; n < 4; ++n)
#pragma unroll
                        for (int ks = 0; ks < 7; ++ks)
                            acc[mt][n] = __builtin_amdgcn_mfma_f32_16x16x32_f16(
                                af[ks], Bf[n][ks], acc[mt][n], 0, 0, 0);
                }
                // C-write (layout: col=lane&15, row=(lane>>4)*4+r)
#pragma unroll
                for (int mt = 0; mt < 2; ++mt)
#pragma unroll
                    for (int n = 0; n < 4; ++n) {
                        const int j = (n0 + n) * 16 + (lane & 15);
                        if (j < U) {
#pragma unroll
                            for (int r = 0; r < 4; ++r) {
                                int t = mh * 32 + mt * 16 + (lane >> 4) * 4 + r;
                                float h = fmaxf(acc[mt][n][r] + b1r[n], 0.f);
                                *(_Float16*)(hb + (uint32_t)t * HROW + 2u * (uint32_t)j) = (_Float16)h;
                            }
                        }
                    }
            }
        }
        __syncthreads();
    }

    // ---- epilogue ----
    if (tid < U) { zf2[0][tid] = x2; zf2[1][tid] = y2; }
    __syncthreads();

    if (tid >= 128 && tid < 328) {
        const int e = tid - 128;
        const int h = e / 100, jq = e - 100 * (e / 100);
        float acc2 = 0.f;
#pragma unroll 4
        for (int kk = 0; kk < 100; ++kk)
            acc2 = fmaf(zf2[h][kk], w2[(100 * h + kk) * U + jq], acc2);
        pb[h][jq] = acc2;
    }
    __syncthreads();

    if (tid < U) h2s[tid] = fmaxf(pb[0][tid] + pb[1][tid] + b2[tid], 0.f);
    __syncthreads();

    if (tid < P) {
        float acc = bp[tid];
#pragma unroll 4
        for (int j = 0; j < U; ++j) acc = fmaf(h2s[j], wp[j * P + tid], acc);
        h3s[tid] = tanhf(acc);
    }
    __syncthreads();

    if (tid < C) {
        float acc = bh[tid];
#pragma unroll
        for (int pp = 0; pp < P; ++pp) acc = fmaf(h3s[pp], wh[pp * C + tid], acc);
        out[b * C + tid] = acc;
    }
}
} // namespace

extern "C" void kernel_launch(void* const* d_in, const int* in_sizes, int n_in,
                              void* d_out, int out_size, void* d_ws, size_t ws_size,
                              hipStream_t stream) {
    const int* xi        = (const int*)d_in[0];
    const float* emb     = (const float*)d_in[1];
    const float* omega1  = (const float*)d_in[2];
    const float* omega2  = (const float*)d_in[3];
    const float* w1      = (const float*)d_in[4];
    const float* b1      = (const float*)d_in[5];
    const float* w2      = (const float*)d_in[6];
    const float* b2      = (const float*)d_in[7];
    const float* wp      = (const float*)d_in[8];
    const float* bp      = (const float*)d_in[9];
    const float* wh      = (const float*)d_in[10];
    const float* bh      = (const float*)d_in[11];
    float* out           = (float*)d_out;

    hipLaunchKernelGGL(donn_kernel, dim3(BATCH), dim3(384), 0, stream,
                       xi, emb, omega1, omega2, w1, b1, w2, b2, wp, bp, wh, bh, out);
}

// Round 6
// 127.924 us; speedup vs baseline: 1.5781x; 1.5781x over previous
//
#include <hip/hip_runtime.h>
#include <cmath>

namespace {
constexpr int T = 1024, BATCH = 128, U = 100, E = 100, P = 20, C = 2;
constexpr int TC = 64, NC = 16;          // chunk size, number of chunks
constexpr float DT = 0.001f, SCALE = 0.2f, MU = 1.0f;
constexpr float DTS = DT * SCALE;

// ---- LDS arena ----
// WL [100 j][464 B]   f16 w1, k'-interleaved (k'=2k | 2(k-U)+1), pads [400,464)=0
// ZB [2][64 t][464 B] f16 z (x_j,y_j)@4j, pads zero           (MFMA A operand)
// EB [2][100 j][128 B] f16 u, [unit][time] rows, chunk-XOR-swizzled
// HB [2][100 j][128 B] f16 h1, [unit][time] rows, chunk-XOR-swizzled
constexpr uint32_t WROW = 464u, ZROW = 464u, EROW = 128u, HROW = 128u;
constexpr uint32_t WLB = 0u;
constexpr uint32_t ZBB = 46400u, ZBUF = 29696u;
constexpr uint32_t EBB = 105792u, EBUF = 12800u;
constexpr uint32_t HBB = 131392u, HBUF = 12800u;
constexpr uint32_t ARENA = 156992u;

typedef _Float16 f16x8 __attribute__((ext_vector_type(8)));
typedef _Float16 f16x4 __attribute__((ext_vector_type(4)));
typedef float f32x4 __attribute__((ext_vector_type(4)));
typedef _Float16 h2_t __attribute__((ext_vector_type(2)));

__device__ __forceinline__ void eul5(float& xx, float& yy, float dom, float ax) {
    constexpr float c0 = 1.0f + DT * MU;   // dom = DT*omega, ax = DT*SCALE*drive
#pragma unroll
    for (int s = 0; s < 5; ++s) {
        float r2 = fmaf(yy, yy, xx * xx);
        float sc = fmaf(-DT, r2, c0);
        float nx = fmaf(xx, sc, fmaf(-dom, yy, ax));
        float ny = fmaf(yy, sc, dom * xx);
        xx = nx; yy = ny;
    }
}

__launch_bounds__(512, 1)
__global__ void donn_kernel(const int* __restrict__ xg,
                            const float* __restrict__ emb,
                            const float* __restrict__ omega1,
                            const float* __restrict__ omega2,
                            const float* __restrict__ w1,
                            const float* __restrict__ b1,
                            const float* __restrict__ w2,
                            const float* __restrict__ b2,
                            const float* __restrict__ wp,
                            const float* __restrict__ bp,
                            const float* __restrict__ wh,
                            const float* __restrict__ bh,
                            float* __restrict__ out)
{
    const int b = blockIdx.x;
    const int tid = threadIdx.x;

    __shared__ __align__(16) char smem[ARENA];
    __shared__ int xs[2][TC];
    __shared__ float zf2[2][104];
    __shared__ float pb[2][104];
    __shared__ float h2s[104];
    __shared__ float h3s[32];

    // ---- per-role persistent state ----
    float x1 = 0.f, y1 = 0.f, x2 = 0.f, y2 = 0.f;
    float dom1 = 0.f, dom2 = 0.f;
    int jc = 0, j2c = 0;
    bool act1 = false;
    int mw = 0, lane = 0, mh = 0, n0 = 0;
    float b1r[4] = {0.f, 0.f, 0.f, 0.f};
    uint32_t brow[4] = {0u, 0u, 0u, 0u};

    if (tid < 128) {                       // osc1: unit j = tid (j<100 active)
        jc = (tid < U) ? tid : (U - 1);
        act1 = tid < U;
        dom1 = DT * omega1[jc];
    } else if (tid < 256) {                // osc2: unit j = tid-128
        const int j2 = tid - 128;
        j2c = (j2 < U) ? j2 : (U - 1);
        dom2 = DT * omega2[j2c];
    } else {                               // mm: 4 waves, MFMA GEMM + emb gather
        mw = (tid >> 6) - 4;               // 0..3
        lane = tid & 63;
        mh = mw >> 1;                      // rows [mh*32, mh*32+32)
        n0 = (mw & 1) * 4;                 // n-tiles n0..n0+3 (tile 7 dummy)
#pragma unroll
        for (int n = 0; n < 4; ++n) {
            int j = (n0 + n) * 16 + (lane & 15);
            int jj = (j < U) ? j : (U - 1);
            b1r[n] = b1[jj];
            brow[n] = WLB + (uint32_t)jj * WROW + 16u * (uint32_t)(lane >> 4);
        }
    }

    // ---- prologue ----
    if (tid < TC) xs[0][tid] = xg[b * T + tid];
    else if (tid < 2 * TC) xs[1][tid - TC] = xg[b * T + TC + (tid - TC)];
    for (int idx = tid; idx < 200 * 100; idx += 512) {      // w1 -> WL
        int k = idx / 100, j = idx - 100 * k;
        int kp = (k < U) ? (2 * k) : (2 * (k - U) + 1);
        *(_Float16*)(smem + WLB + (uint32_t)j * WROW + 2u * (uint32_t)kp) = (_Float16)w1[k * U + j];
    }
    for (int idx = tid; idx < 100 * 16; idx += 512) {       // WL pads
        int row = idx >> 4, wd = idx & 15;
        *(float*)(smem + WLB + (uint32_t)row * WROW + 400u + 4u * (uint32_t)wd) = 0.f;
    }
    for (int idx = tid; idx < 128 * 16; idx += 512) {       // ZB pads
        int zr = idx >> 4, wd = idx & 15;
        uint32_t base = ZBB + (uint32_t)(zr >> 6) * ZBUF + (uint32_t)(zr & 63) * ZROW;
        *(float*)(smem + base + 400u + 4u * (uint32_t)wd) = 0.f;
    }
    __syncthreads();
    for (int idx = tid; idx < 100 * TC; idx += 512) {       // EB[0] = chunk 0
        int j = idx >> 6, t = idx & 63;
        int tok = xs[0][t];
        uint32_t off = EBB + (uint32_t)j * EROW
                     + (uint32_t)(((((t >> 3) ^ (j & 7))) << 4) + 2 * (t & 7));
        *(_Float16*)(smem + off) = (_Float16)emb[tok * E + j];
    }
    __syncthreads();

    // ---- 3-stage chunked pipeline, one barrier per phase ----
    // phase p: osc1 chunk p (EB[p&1] -> ZB[p&1]); mm: gather chunk p+1 -> EB[(p+1)&1],
    // MFMA chunk p-1 (ZB[(p-1)&1] -> HB[(p-1)&1]); osc2 chunk p-2 (HB[p&1]).
    for (int p = 0; p <= NC + 1; ++p) {
        if (tid < 128) {
            if (tid < TC && p + 2 < NC)
                xs[p & 1][tid] = xg[b * T + (p + 2) * TC + tid];
            if (p < NC) {
                const uint32_t q = (uint32_t)(p & 1);
                const char* ebase = smem + EBB + q * EBUF + (uint32_t)jc * EROW;
                char* zbase = smem + ZBB + q * ZBUF + 4u * (uint32_t)jc;
                const int s = jc & 7;
                f16x8 eA = *(const f16x8*)(ebase + ((0 ^ s) << 4));
                for (int gg = 0; gg < 4; ++gg) {
                    f16x8 eB = *(const f16x8*)(ebase + (((2 * gg + 1) ^ s) << 4));
                    {
                        char* zt = zbase + (uint32_t)(16 * gg) * ZROW;
#pragma unroll
                        for (int i = 0; i < 8; ++i) {
                            eul5(x1, y1, dom1, DTS * (float)eA[i]);
                            if (act1) {
                                h2_t zz; zz[0] = (_Float16)x1; zz[1] = (_Float16)y1;
                                *(h2_t*)(zt + (uint32_t)i * ZROW) = zz;
                            }
                        }
                    }
                    if (gg < 3) eA = *(const f16x8*)(ebase + (((2 * gg + 2) ^ s) << 4));
                    {
                        char* zt = zbase + (uint32_t)(16 * gg + 8) * ZROW;
#pragma unroll
                        for (int i = 0; i < 8; ++i) {
                            eul5(x1, y1, dom1, DTS * (float)eB[i]);
                            if (act1) {
                                h2_t zz; zz[0] = (_Float16)x1; zz[1] = (_Float16)y1;
                                *(h2_t*)(zt + (uint32_t)i * ZROW) = zz;
                            }
                        }
                    }
                }
            }
        } else if (tid < 256) {
            if (p >= 2) {
                const uint32_t q = (uint32_t)(p & 1);   // chunk p-2 parity
                const char* hbase = smem + HBB + q * HBUF + (uint32_t)j2c * HROW;
                const int s = j2c & 7;
                f16x8 eA = *(const f16x8*)(hbase + ((0 ^ s) << 4));
                for (int gg = 0; gg < 4; ++gg) {
                    f16x8 eB = *(const f16x8*)(hbase + (((2 * gg + 1) ^ s) << 4));
#pragma unroll
                    for (int i = 0; i < 8; ++i)
                        eul5(x2, y2, dom2, DTS * (float)eA[i]);
                    if (gg < 3) eA = *(const f16x8*)(hbase + (((2 * gg + 2) ^ s) << 4));
#pragma unroll
                    for (int i = 0; i < 8; ++i)
                        eul5(x2, y2, dom2, DTS * (float)eB[i]);
                }
            }
        } else {
            // A) issue emb gather for chunk p+1 (1 base + 25 imm-offset loads)
            float er[25];
            const bool edo = (p + 1 < NC);
            if (edo) {
                const uint32_t qe = (uint32_t)((p + 1) & 1);
                int tok = xs[qe][lane];                 // lane == timestep
                const float* ep = emb + (size_t)tok * E;
#pragma unroll
                for (int i = 0; i < 25; ++i) er[i] = ep[mw * 25 + i];
            }
            // B) MFMA GEMM chunk p-1: C[64t x 100j] = z[64x224] * w1'[224x100]
            if (p >= 1 && p <= NC) {
                const uint32_t qm = (uint32_t)((p - 1) & 1);
                const char* zb = smem + ZBB + qm * ZBUF;
                f32x4 acc[2][4];
#pragma unroll
                for (int mt = 0; mt < 2; ++mt)
#pragma unroll
                    for (int n = 0; n < 4; ++n) acc[mt][n] = (f32x4)0.f;
#pragma unroll
                for (int mt = 0; mt < 2; ++mt) {
                    const uint32_t ar = (uint32_t)(mh * 32 + mt * 16 + (lane & 15)) * ZROW
                                        + 16u * (uint32_t)(lane >> 4);
                    f16x8 af[7];
#pragma unroll
                    for (int ks = 0; ks < 7; ++ks)
                        af[ks] = *(const f16x8*)(zb + ar + 64u * ks);
#pragma unroll
                    for (int n = 0; n < 4; ++n)
#pragma unroll
                        for (int ks = 0; ks < 7; ++ks) {
                            f16x8 bf = *(const f16x8*)(smem + brow[n] + 64u * ks);
                            acc[mt][n] = __builtin_amdgcn_mfma_f32_16x16x32_f16(
                                af[ks], bf, acc[mt][n], 0, 0, 0);
                        }
                }
                // C-write (col=lane&15, row=(lane>>4)*4+r) -> HB[j][t] b64-packed
                char* hb = smem + HBB + qm * HBUF;
#pragma unroll
                for (int mt = 0; mt < 2; ++mt)
#pragma unroll
                    for (int n = 0; n < 4; ++n) {
                        const int j = (n0 + n) * 16 + (lane & 15);
                        if (j < U) {
                            const int t0v = mh * 32 + mt * 16 + (lane >> 4) * 4;
                            f16x4 hv;
#pragma unroll
                            for (int r = 0; r < 4; ++r)
                                hv[r] = (_Float16)fmaxf(acc[mt][n][r] + b1r[n], 0.f);
                            uint32_t off = (uint32_t)j * HROW
                                + (uint32_t)(((((t0v >> 3) ^ (j & 7))) << 4) + ((2 * t0v) & 15));
                            *(f16x4*)(hb + off) = hv;
                        }
                    }
            }
            // C) write back gathered emb (vmcnt waits land here, after MFMA)
            if (edo) {
                const uint32_t qe = (uint32_t)((p + 1) & 1);
                char* eb = smem + EBB + qe * EBUF;
#pragma unroll
                for (int i = 0; i < 25; ++i) {
                    int jrow = mw * 25 + i;
                    uint32_t off = (uint32_t)jrow * EROW
                        + (uint32_t)(((((lane >> 3) ^ (jrow & 7))) << 4) + 2 * (lane & 7));
                    *(_Float16*)(eb + off) = (_Float16)er[i];
                }
            }
        }
        __syncthreads();
    }

    // ---- epilogue ----
    if (tid >= 128 && tid < 256) {
        const int j = tid - 128;
        if (j < U) { zf2[0][j] = x2; zf2[1][j] = y2; }
    }
    __syncthreads();

    if (tid >= 256 && tid < 456) {
        const int e = tid - 256;
        const int h = e / 100, jq = e - 100 * (e / 100);
        float acc2 = 0.f;
#pragma unroll 4
        for (int kk = 0; kk < 100; ++kk)
            acc2 = fmaf(zf2[h][kk], w2[(100 * h + kk) * U + jq], acc2);
        pb[h][jq] = acc2;
    }
    __syncthreads();

    if (tid < U) h2s[tid] = fmaxf(pb[0][tid] + pb[1][tid] + b2[tid], 0.f);
    __syncthreads();

    if (tid < P) {
        float acc = bp[tid];
#pragma unroll 4
        for (int j = 0; j < U; ++j) acc = fmaf(h2s[j], wp[j * P + tid], acc);
        h3s[tid] = tanhf(acc);
    }
    __syncthreads();

    if (tid < C) {
        float acc = bh[tid];
#pragma unroll
        for (int pp = 0; pp < P; ++pp) acc = fmaf(h3s[pp], wh[pp * C + tid], acc);
        out[b * C + tid] = acc;
    }
}
} // namespace

extern "C" void kernel_launch(void* const* d_in, const int* in_sizes, int n_in,
                              void* d_out, int out_size, void* d_ws, size_t ws_size,
                              hipStream_t stream) {
    const int* xi        = (const int*)d_in[0];
    const float* emb     = (const float*)d_in[1];
    const float* omega1  = (const float*)d_in[2];
    const float* omega2  = (const float*)d_in[3];
    const float* w1      = (const float*)d_in[4];
    const float* b1      = (const float*)d_in[5];
    const float* w2      = (const float*)d_in[6];
    const float* b2      = (const float*)d_in[7];
    const float* wp      = (const float*)d_in[8];
    const float* bp      = (const float*)d_in[9];
    const float* wh      = (const float*)d_in[10];
    const float* bh      = (const float*)d_in[11];
    float* out           = (float*)d_out;

    hipLaunchKernelGGL(donn_kernel, dim3(BATCH), dim3(512), 0, stream,
                       xi, emb, omega1, omega2, w1, b1, w2, b2, wp, bp, wh, bh, out);
}